// Round 6
// baseline (248.714 us; speedup 1.0000x reference)
//
#include <hip/hip_runtime.h>

// out[(b*8+r), i, j] = softmax_j( 0.125 * sum_{h, s%8==r} q[b,s,h,i]*k[b,s,h,j] )
// value input is dead (DCE'd under jit in the reference).
// q/k: [2, 16384, 8, 64] fp32; the 512 floats of (s, h=0..7, d=0..63) are contiguous.
#define NS 16384
#define BUCKETS 16

// ---------------- Stage 1: partial Gram tiles, register-only ----------------
// grid = BUCKETS*bpb blocks, 256 threads = 4 waves, no LDS, no barriers.
// Wave w owns the 32x32 quadrant (rows (w>>1)*32.., cols (w&1)*32..); lane = 4x4.
// Inner loop: explicit 2-deep register double-buffer (quantum = 4 h-rows,
// 8 float4 global loads) so ~8-16 loads are in flight while FMAs run —
// round-5 failure was the compiler holding only 2 buffers (VGPR_Count=32).
__global__ __launch_bounds__(256, 4) void gram_partial(
    const float* __restrict__ Q, const float* __restrict__ K,
    float* __restrict__ part, int bpb, int spb)
{
    const int bid    = blockIdx.x;
    const int bucket = bid / bpb;
    const int chunk  = bid % bpb;
    const int b      = bucket >> 3;
    const int r      = bucket & 7;

    const int lane = threadIdx.x & 63;
    const int wv   = threadIdx.x >> 6;
    const int ty   = lane >> 3;                  // 0..7
    const int tx   = lane & 7;                   // 0..7
    const int qcol = (wv >> 1) * 32 + ty * 4;    // C-row block (q dim i)
    const int kcol = (wv & 1) * 32 + tx * 4;     // C-col block (k dim j)

    const size_t tb = (size_t)b * ((size_t)NS * 512) + (size_t)r * 512
                    + (size_t)(chunk * spb) * 4096;
    const float* qb = Q + tb + qcol;
    const float* kb = K + tb + kcol;

    float acc[4][4] = {};
    float4 qA[4], kA[4], qB[4], kB[4];

    // quantum = 4 h-rows (h 0..3 at offset 0, h 4..7 at offset 256 floats)
    auto ld4 = [&](float4* q4, float4* k4, const float* bq, const float* bk) {
        #pragma unroll
        for (int h = 0; h < 4; ++h) {
            q4[h] = *(const float4*)(bq + h * 64);
            k4[h] = *(const float4*)(bk + h * 64);
        }
    };
    auto fma4 = [&](const float4* q4, const float4* k4) {
        #pragma unroll
        for (int h = 0; h < 4; ++h) {
            const float qa[4] = {q4[h].x, q4[h].y, q4[h].z, q4[h].w};
            const float ka[4] = {k4[h].x, k4[h].y, k4[h].z, k4[h].w};
            #pragma unroll
            for (int ii = 0; ii < 4; ++ii)
                #pragma unroll
                for (int jj = 0; jj < 4; ++jj)
                    acc[ii][jj] += qa[ii] * ka[jj];
        }
    };

    ld4(qA, kA, qb, kb);                      // s_hi 0, first half
    for (int s = 0; s < spb - 1; ++s) {
        ld4(qB, kB, qb + 256, kb + 256);      // this s_hi, second half
        fma4(qA, kA);
        qb += 4096; kb += 4096;               // next s_hi (s stride = 8 rows)
        ld4(qA, kA, qb, kb);                  // next s_hi, first half
        fma4(qB, kB);
    }
    ld4(qB, kB, qb + 256, kb + 256);          // epilogue
    fma4(qA, kA);
    fma4(qB, kB);

    // write this wave's quadrant of the block's 64x64 partial
    float* p = part + (size_t)bid * 4096
             + (size_t)((wv >> 1) * 32) * 64 + (wv & 1) * 32;
    #pragma unroll
    for (int ii = 0; ii < 4; ++ii) {
        float4 v = make_float4(acc[ii][0], acc[ii][1], acc[ii][2], acc[ii][3]);
        *(float4*)(p + (ty * 4 + ii) * 64 + tx * 4) = v;
    }
}

// ---------------- Stage 2: reduce partials + fused row softmax ----------------
// grid = 16 buckets * 64 rows = 1024 blocks, 256 threads.
// Thread (c = tid&63, sl = tid>>6): sums `slices` partials (independent,
// coalesced 256B/wave loads), LDS cross-wave reduce, in-wave softmax.
__global__ __launch_bounds__(256) void reduce_softmax(
    const float* __restrict__ part, float* __restrict__ out, int slices)
{
    const int g   = blockIdx.x >> 6;
    const int row = blockIdx.x & 63;
    const int c   = threadIdx.x & 63;
    const int sl  = threadIdx.x >> 6;

    const float* p = part + (size_t)(g * (slices * 4) + sl * slices) * 4096
                          + row * 64 + c;
    float s = 0.f;
    #pragma unroll 4
    for (int k = 0; k < slices; ++k) s += p[(size_t)k * 4096];

    __shared__ float red[4][64];
    red[sl][c] = s;
    __syncthreads();
    if (sl == 0) {
        float v = (red[0][c] + red[1][c]) + (red[2][c] + red[3][c]);
        v *= 0.125f;   // SCALE = 1/sqrt(64)
        float m = v;
        #pragma unroll
        for (int o = 32; o; o >>= 1) m = fmaxf(m, __shfl_xor(m, o));
        const float e = __expf(v - m);
        float sum = e;
        #pragma unroll
        for (int o = 32; o; o >>= 1) sum += __shfl_xor(sum, o);
        out[(size_t)g * 4096 + row * 64 + c] = e / sum;
    }
}

// ---------------- launch ----------------
extern "C" void kernel_launch(void* const* d_in, const int* in_sizes, int n_in,
                              void* d_out, int out_size, void* d_ws, size_t ws_size,
                              hipStream_t stream)
{
    const float* Q = (const float*)d_in[0];
    const float* K = (const float*)d_in[1];
    // d_in[2] (value) is dead in the reference -> never read.
    float* out  = (float*)d_out;
    float* part = (float*)d_ws;

    int bpb = 64;   // 1024 blocks, 16.7 MB workspace
    while ((size_t)BUCKETS * bpb * 4096 * sizeof(float) > ws_size && bpb > 4) bpb >>= 1;
    const int spb = 2048 / bpb;   // s_hi per block

    gram_partial<<<dim3(BUCKETS * bpb), dim3(256), 0, stream>>>(Q, K, part, bpb, spb);
    reduce_softmax<<<dim3(1024), dim3(256), 0, stream>>>(part, out, bpb / 4);
}

// Round 9
// 194.880 us; speedup vs baseline: 1.2762x; 1.2762x over previous
//
#include <hip/hip_runtime.h>

// out[(b*8+r), i, j] = softmax_j( 0.125 * sum_{h, s%8==r} q[b,s,h,i]*k[b,s,h,j] )
// value input is dead (DCE'd under jit in the reference).
// q/k: [2, 16384, 8, 64] fp32; the 512 floats of (s, h=0..7, d=0..63) are contiguous.
#define NS 16384
#define BUCKETS 16
#define DEPTH 4   // LDS pipeline depth (s_hi quanta in flight)

__device__ __forceinline__ void gload_lds16(const float* g, float* l) {
    __builtin_amdgcn_global_load_lds(
        (const __attribute__((address_space(1))) void*)g,
        (__attribute__((address_space(3))) void*)l,
        16 /*bytes/lane*/, 0, 0);
}

// ---------------- Stage 1: per-wave 64x64 partial Gram, deep-pipelined ----------
// grid = BUCKETS*C one-WAVE blocks (64 threads). No barriers anywhere: vmcnt is
// per-wave, and global_load_lds has no dest VGPR so the compiler cannot sink
// the prefetch (round-6 failure: source-level reg double-buffer was collapsed
// to 2 loads in flight, VGPR_Count=48). 4 buffers x 4KB; counted s_waitcnt
// vmcnt(4*ahead) gates each buffer; lane owns an 8x8 acc tile (64 regs).
__global__ __launch_bounds__(64, 4) void gram_wave(
    const float* __restrict__ Q, const float* __restrict__ K,
    float* __restrict__ part, int C, int spb)
{
    const int bid    = blockIdx.x;
    const int bucket = bid / C;
    const int chunk  = bid % C;
    const int b      = bucket >> 3;
    const int r      = bucket & 7;

    const int lane = threadIdx.x;   // 0..63 (one wave)
    const int ty   = lane >> 3;     // acc rows ty*8..+7  (q dim i)
    const int tx   = lane & 7;      // acc cols tx*8..+7  (k dim j)

    __shared__ __align__(16) float buf[DEPTH][1024]; // [0..511]=q row, [512..1023]=k row

    const size_t tb = (size_t)b * ((size_t)NS * 512) + (size_t)r * 512
                    + (size_t)chunk * spb * 4096;
    const float* gq = Q + tb + lane * 4;
    const float* gk = K + tb + lane * 4;

    auto stage = [&](int i) {   // stage s_hi quantum i: 4 vmem instrs, 4KB
        const size_t off = (size_t)i * 4096;   // s_hi stride = 8 rows * 512 floats
        float* d = buf[i & (DEPTH - 1)];
        gload_lds16(gq + off,       d);
        gload_lds16(gq + off + 256, d + 256);
        gload_lds16(gk + off,       d + 512);
        gload_lds16(gk + off + 256, d + 768);
    };

    float acc[8][8] = {};

    #pragma unroll
    for (int i = 0; i < DEPTH - 1; ++i) stage(i);   // prologue: 3 buffers ahead

    for (int it = 0; it < spb; ++it) {
        if (it + DEPTH - 1 < spb) stage(it + DEPTH - 1);
        const int ahead = min(spb - 1 - it, DEPTH - 1);  // staged quanta ahead of it
        if      (ahead >= 3) asm volatile("s_waitcnt vmcnt(12)" ::: "memory");
        else if (ahead == 2) asm volatile("s_waitcnt vmcnt(8)"  ::: "memory");
        else if (ahead == 1) asm volatile("s_waitcnt vmcnt(4)"  ::: "memory");
        else                 asm volatile("s_waitcnt vmcnt(0)"  ::: "memory");
        __builtin_amdgcn_sched_barrier(0);

        const float* bq = buf[it & (DEPTH - 1)];
        const float* bk = bq + 512;
        #pragma unroll
        for (int tr = 0; tr < 8; ++tr) {   // 8 heads in this s_hi
            const float4 q0 = *(const float4*)(bq + tr * 64 + ty * 8);
            const float4 q1 = *(const float4*)(bq + tr * 64 + ty * 8 + 4);
            const float4 k0 = *(const float4*)(bk + tr * 64 + tx * 8);
            const float4 k1 = *(const float4*)(bk + tr * 64 + tx * 8 + 4);
            const float qa[8] = {q0.x,q0.y,q0.z,q0.w,q1.x,q1.y,q1.z,q1.w};
            const float ka[8] = {k0.x,k0.y,k0.z,k0.w,k1.x,k1.y,k1.z,k1.w};
            #pragma unroll
            for (int ii = 0; ii < 8; ++ii)
                #pragma unroll
                for (int jj = 0; jj < 8; ++jj)
                    acc[ii][jj] += qa[ii] * ka[jj];
        }
    }

    float* p = part + (size_t)bid * 4096 + (size_t)(ty * 8) * 64 + tx * 8;
    #pragma unroll
    for (int ii = 0; ii < 8; ++ii) {
        *(float4*)(p + ii * 64)     = make_float4(acc[ii][0], acc[ii][1], acc[ii][2], acc[ii][3]);
        *(float4*)(p + ii * 64 + 4) = make_float4(acc[ii][4], acc[ii][5], acc[ii][6], acc[ii][7]);
    }
}

// ---------------- Stage 2: reduce partials + fused row softmax ----------------
// grid = 16 buckets * 64 rows = 1024 blocks, 256 threads.
// Thread (c = tid&63, sl = tid>>6): sums `slices` partials (independent,
// coalesced 256B/wave loads), LDS cross-wave reduce, in-wave softmax.
__global__ __launch_bounds__(256) void reduce_softmax(
    const float* __restrict__ part, float* __restrict__ out, int slices)
{
    const int g   = blockIdx.x >> 6;
    const int row = blockIdx.x & 63;
    const int c   = threadIdx.x & 63;
    const int sl  = threadIdx.x >> 6;

    const float* p = part + (size_t)(g * (slices * 4) + sl * slices) * 4096
                          + row * 64 + c;
    float s = 0.f;
    #pragma unroll 4
    for (int k = 0; k < slices; ++k) s += p[(size_t)k * 4096];

    __shared__ float red[4][64];
    red[sl][c] = s;
    __syncthreads();
    if (sl == 0) {
        float v = (red[0][c] + red[1][c]) + (red[2][c] + red[3][c]);
        v *= 0.125f;   // SCALE = 1/sqrt(64)
        float m = v;
        #pragma unroll
        for (int o = 32; o; o >>= 1) m = fmaxf(m, __shfl_xor(m, o));
        const float e = __expf(v - m);
        float sum = e;
        #pragma unroll
        for (int o = 32; o; o >>= 1) sum += __shfl_xor(sum, o);
        out[(size_t)g * 4096 + row * 64 + c] = e / sum;
    }
}

// ---------------- launch ----------------
extern "C" void kernel_launch(void* const* d_in, const int* in_sizes, int n_in,
                              void* d_out, int out_size, void* d_ws, size_t ws_size,
                              hipStream_t stream)
{
    const float* Q = (const float*)d_in[0];
    const float* K = (const float*)d_in[1];
    // d_in[2] (value) is dead in the reference -> never read.
    float* out  = (float*)d_out;
    float* part = (float*)d_ws;

    int C = 128;   // chunks per bucket; 2048 waves, 33.6 MB workspace if it fits
    while ((size_t)BUCKETS * C * 4096 * sizeof(float) > ws_size && C > 4) C >>= 1;
    const int spb = 2048 / C;   // s_hi per wave (>= DEPTH)

    gram_wave<<<dim3(BUCKETS * C), dim3(64), 0, stream>>>(Q, K, part, C, spb);
    reduce_softmax<<<dim3(1024), dim3(256), 0, stream>>>(part, out, C / 4);
}